// Round 1
// baseline (635.116 us; speedup 1.0000x reference)
//
#include <hip/hip_runtime.h>

// Problem constants
#define C_IN   48
#define C3     144
#define HW     56
#define SSP    3136          // 56*56
#define NWIN   64            // (56*56)/49
#define DW     49            // window size w*w
#define DP     56            // padded head dim (cols 49..55 zero)
#define NROWS  9216          // NWIN * C3

// Attention tiling
#define BM     64
#define BN     64
#define NSPLIT 2
#define KT_PER (NROWS / NSPLIT)   // 4608
#define NTILE  (KT_PER / BN)      // 72

// ws layout (floats):
//   yf    : [0, 516096)                 9216*56   (also reused as yhat after attn)
//   opart : [516096, 516096+1032192)    2*9216*56
//   mpart : next 18432
//   lpart : next 18432
#define YF_OFF    0
#define OPART_OFF 516096
#define MPART_OFF (516096 + 1032192)
#define LPART_OFF (MPART_OFF + 18432)
#define YHAT_OFF  0   // alias yf (yf dead after attention)

// ---------------------------------------------------------------------------
// Kernel 1: depthwise convs (3x3 / 5x5 / 7x7), written directly in attention
// row layout: yf[r*56 + t], r = g*144 + c3, t in [0,49) -> flat pixel g*49+t.
// Cols 49..55 are zero pad.
// ---------------------------------------------------------------------------
__global__ __launch_bounds__(256) void conv_kernel(
    const float* __restrict__ x,
    const float* __restrict__ w3,
    const float* __restrict__ w5,
    const float* __restrict__ w7,
    float* __restrict__ yf) {
  int idx = blockIdx.x * 256 + threadIdx.x;   // r*56 + t
  if (idx >= NROWS * DP) return;
  int r = idx / DP, t = idx - r * DP;
  float val = 0.f;
  if (t < DW) {
    int g = r / C3, c3 = r - g * C3;
    int flat = g * DW + t;
    int h = flat / HW, w = flat - h * HW;
    int grp = c3 / C_IN, c = c3 - grp * C_IN;
    const float* wk;
    int ks;
    if (grp == 0)      { wk = w3 + c * 9;  ks = 3; }
    else if (grp == 1) { wk = w5 + c * 25; ks = 5; }
    else               { wk = w7 + c * 49; ks = 7; }
    int p = ks >> 1;
    const float* xc = x + c * SSP;
    for (int dy = 0; dy < ks; dy++) {
      int hy = h + dy - p;
      if (hy < 0 || hy >= HW) continue;
      const float* xr = xc + hy * HW;
      const float* wr = wk + dy * ks;
      for (int dx = 0; dx < ks; dx++) {
        int wx = w + dx - p;
        if (wx < 0 || wx >= HW) continue;
        val += xr[wx] * wr[dx];
      }
    }
  }
  yf[idx] = val;
}

// ---------------------------------------------------------------------------
// Kernel 2: split-K flash attention (fp32). Q=K=V=yf (9216 x 49, stride 56).
// Grid: (144 query tiles of 64 rows) x (2 key splits of 4608 keys).
// Block: 256 threads = 16(tx) x 16(ty). Micro-tile 4x4: m = 4*ty+i, n/d = 4*tx+j.
// ---------------------------------------------------------------------------
__global__ __launch_bounds__(256) void attn_kernel(
    const float* __restrict__ yf,
    float* __restrict__ opart,
    float* __restrict__ mpart,
    float* __restrict__ lpart) {
  // Qt[d][m]                 : stride 64, read float4 @ [d*64 + 4*ty]
  // Kt[d][n'] rotated        : n' = (n + (d & ~3)) & 63; float4 reads 2-way max
  // Kn[n][d]                 : stride 68 (16B aligned rows, banks spread)
  // Pm[m][n]                 : stride 66 (conflict-free scalar reads over ty)
  __shared__ float Qt[DP * 64];
  __shared__ float Kt[DP * 64];
  __shared__ float Kn[64 * 68];
  __shared__ float Pm[64 * 66];

  const int tid = threadIdx.x;
  const int tx = tid & 15, ty = tid >> 4;
  const int qt = blockIdx.x, sp = blockIdx.y;
  const int q0 = qt * BM;

  // Stage Q (transposed, pre-scaled by 1/49). Once per block.
  for (int c = tid; c < 64 * 14; c += 256) {
    int m = c / 14, db = (c - m * 14) * 4;
    const float4 v = *(const float4*)&yf[(q0 + m) * DP + db];
    Qt[(db + 0) * 64 + m] = v.x * (1.f / 49.f);
    Qt[(db + 1) * 64 + m] = v.y * (1.f / 49.f);
    Qt[(db + 2) * 64 + m] = v.z * (1.f / 49.f);
    Qt[(db + 3) * 64 + m] = v.w * (1.f / 49.f);
  }
  // Zero Kn pad cols 56..63 (persist across tiles)
  for (int c = tid; c < 64 * 8; c += 256) {
    int n = c >> 3, d = 56 + (c & 7);
    Kn[n * 68 + d] = 0.f;
  }

  float mi[4], li[4], o[4][4];
#pragma unroll
  for (int i = 0; i < 4; i++) {
    mi[i] = -1e30f; li[i] = 0.f;
#pragma unroll
    for (int j = 0; j < 4; j++) o[i][j] = 0.f;
  }

  const int k0base = sp * KT_PER;
  for (int kt = 0; kt < NTILE; kt++) {
    const int k0 = k0base + kt * BN;
    __syncthreads();  // prior tile's readers of Kn/Kt/Pm done
    // Stage K tile: coalesced global float4, write both layouts
    for (int c = tid; c < 64 * 14; c += 256) {
      int n = c / 14, db = (c - n * 14) * 4;
      const float4 v = *(const float4*)&yf[(k0 + n) * DP + db];
      *(float4*)&Kn[n * 68 + db] = v;
      int rot = (n + db) & 63;  // db is already (d & ~3) for these 4 d's
      Kt[(db + 0) * 64 + rot] = v.x;
      Kt[(db + 1) * 64 + rot] = v.y;
      Kt[(db + 2) * 64 + rot] = v.z;
      Kt[(db + 3) * 64 + rot] = v.w;
    }
    __syncthreads();

    // ---- scores: S[4][4] = (Q/49) . K over d in [0,56) ----
    float s[4][4];
#pragma unroll
    for (int i = 0; i < 4; i++)
#pragma unroll
      for (int j = 0; j < 4; j++) s[i][j] = 0.f;

#pragma unroll 4
    for (int d = 0; d < DP; d++) {
      float a[4], b[4];
      *(float4*)a = *(const float4*)&Qt[d * 64 + 4 * ty];
      int base = (4 * tx + (d & ~3)) & 63;
      *(float4*)b = *(const float4*)&Kt[d * 64 + base];
#pragma unroll
      for (int i = 0; i < 4; i++)
#pragma unroll
        for (int j = 0; j < 4; j++) s[i][j] += a[i] * b[j];
    }

    // ---- online softmax update + write P to LDS ----
#pragma unroll
    for (int i = 0; i < 4; i++) {
      float rm = fmaxf(fmaxf(s[i][0], s[i][1]), fmaxf(s[i][2], s[i][3]));
      rm = fmaxf(rm, __shfl_xor(rm, 1));
      rm = fmaxf(rm, __shfl_xor(rm, 2));
      rm = fmaxf(rm, __shfl_xor(rm, 4));
      rm = fmaxf(rm, __shfl_xor(rm, 8));
      float mn = fmaxf(mi[i], rm);
      float sc = __expf(mi[i] - mn);
      mi[i] = mn;
      float p[4];
      float rs = 0.f;
#pragma unroll
      for (int j = 0; j < 4; j++) { p[j] = __expf(s[i][j] - mn); rs += p[j]; }
      rs += __shfl_xor(rs, 1);
      rs += __shfl_xor(rs, 2);
      rs += __shfl_xor(rs, 4);
      rs += __shfl_xor(rs, 8);
      li[i] = li[i] * sc + rs;
#pragma unroll
      for (int j = 0; j < 4; j++) o[i][j] *= sc;
      *(float2*)&Pm[(4 * ty + i) * 66 + 4 * tx]     = make_float2(p[0], p[1]);
      *(float2*)&Pm[(4 * ty + i) * 66 + 4 * tx + 2] = make_float2(p[2], p[3]);
    }
    __syncthreads();

    // ---- accumulate O += P * K  (o[m=4ty+i][d=4tx+j]) ----
#pragma unroll 4
    for (int n = 0; n < BN; n++) {
      float kv[4];
      *(float4*)kv = *(const float4*)&Kn[n * 68 + 4 * tx];
      float p0 = Pm[(4 * ty + 0) * 66 + n];
      float p1 = Pm[(4 * ty + 1) * 66 + n];
      float p2 = Pm[(4 * ty + 2) * 66 + n];
      float p3 = Pm[(4 * ty + 3) * 66 + n];
#pragma unroll
      for (int j = 0; j < 4; j++) {
        o[0][j] += p0 * kv[j];
        o[1][j] += p1 * kv[j];
        o[2][j] += p2 * kv[j];
        o[3][j] += p3 * kv[j];
      }
    }
  }

  // write partials (unnormalized o, running m and l)
  const int rbase = sp * NROWS + q0;
  if (4 * tx < DP) {
#pragma unroll
    for (int i = 0; i < 4; i++) {
      float4 v = make_float4(o[i][0], o[i][1], o[i][2], o[i][3]);
      *(float4*)&opart[(rbase + 4 * ty + i) * DP + 4 * tx] = v;
    }
  }
  if (tx == 0) {
#pragma unroll
    for (int i = 0; i < 4; i++) {
      mpart[rbase + 4 * ty + i] = mi[i];
      lpart[rbase + 4 * ty + i] = li[i];
    }
  }
}

// ---------------------------------------------------------------------------
// Kernel 3: merge the 2 split partials, normalize, and scatter into the
// WINDOWED output layout: r = g*144+c3, g = nh*8+nw, t = t1*7+t2,
// yhat[c3][h= nh*7+t1][w= nw*7+t2].
// ---------------------------------------------------------------------------
__global__ __launch_bounds__(256) void merge_kernel(
    const float* __restrict__ opart,
    const float* __restrict__ mpart,
    const float* __restrict__ lpart,
    float* __restrict__ yhat) {
  int idx = blockIdx.x * 256 + threadIdx.x;  // r*49 + t
  if (idx >= NROWS * DW) return;
  int r = idx / DW, t = idx - r * DW;
  float m0 = mpart[r], m1 = mpart[NROWS + r];
  float l0 = lpart[r], l1 = lpart[NROWS + r];
  float M = fmaxf(m0, m1);
  float w0 = __expf(m0 - M), w1 = __expf(m1 - M);
  float L = l0 * w0 + l1 * w1;
  float v = (opart[r * DP + t] * w0 + opart[(NROWS + r) * DP + t] * w1) / L;
  int g = r / C3, c3 = r - g * C3;
  int nh = g >> 3, nw = g & 7;
  int t1 = t / 7, t2 = t - t1 * 7;
  int h = nh * 7 + t1, w = nw * 7 + t2;
  yhat[c3 * SSP + h * HW + w] = v;
}

// ---------------------------------------------------------------------------
// Kernel 4: pointwise 48x144 + bias + residual. out[o][s] fp32.
// ---------------------------------------------------------------------------
__global__ __launch_bounds__(256) void pw_kernel(
    const float* __restrict__ x,
    const float* __restrict__ pw,
    const float* __restrict__ pb,
    const float* __restrict__ yhat,
    float* __restrict__ out) {
  int idx = blockIdx.x * 256 + threadIdx.x;  // (o, s/4)
  if (idx >= C_IN * (SSP / 4)) return;
  int o = idx / (SSP / 4), s = (idx - o * (SSP / 4)) * 4;
  float4 acc = *(const float4*)&x[o * SSP + s];
  float b = pb[o];
  acc.x += b; acc.y += b; acc.z += b; acc.w += b;
  const float* pwo = pw + o * C3;
  for (int i = 0; i < C3; i++) {
    float w = pwo[i];
    float4 v = *(const float4*)&yhat[i * SSP + s];
    acc.x += w * v.x; acc.y += w * v.y; acc.z += w * v.z; acc.w += w * v.w;
  }
  *(float4*)&out[o * SSP + s] = acc;
}

// ---------------------------------------------------------------------------
extern "C" void kernel_launch(void* const* d_in, const int* in_sizes, int n_in,
                              void* d_out, int out_size, void* d_ws, size_t ws_size,
                              hipStream_t stream) {
  const float* x  = (const float*)d_in[0];
  const float* w3 = (const float*)d_in[1];
  const float* w5 = (const float*)d_in[2];
  const float* w7 = (const float*)d_in[3];
  const float* pw = (const float*)d_in[4];
  const float* pb = (const float*)d_in[5];
  float* out = (float*)d_out;
  float* ws = (float*)d_ws;

  float* yf    = ws + YF_OFF;
  float* opart = ws + OPART_OFF;
  float* mpart = ws + MPART_OFF;
  float* lpart = ws + LPART_OFF;
  float* yhat  = ws + YHAT_OFF;  // aliases yf (yf dead after attention)

  conv_kernel<<<(NROWS * DP) / 256, 256, 0, stream>>>(x, w3, w5, w7, yf);
  attn_kernel<<<dim3(NROWS / BM, NSPLIT), 256, 0, stream>>>(yf, opart, mpart, lpart);
  merge_kernel<<<(NROWS * DW) / 256, 256, 0, stream>>>(opart, mpart, lpart, yhat);
  pw_kernel<<<(C_IN * SSP / 4) / 256, 256, 0, stream>>>(x, pw, pb, yhat, out);
}

// Round 2
// 180.442 us; speedup vs baseline: 3.5198x; 3.5198x over previous
//
#include <hip/hip_runtime.h>

typedef unsigned int uint;
typedef unsigned short ushort;
typedef __attribute__((ext_vector_type(8))) short bf16x8;   // MFMA A/B frag (8 bf16)
typedef __attribute__((ext_vector_type(4))) float f32x4;    // MFMA C/D frag

// Problem constants
#define C_IN   48
#define C3     144
#define HW     56
#define SSP    3136
#define DW     49
#define DPAD   64            // padded head dim (cols 49..63 zero)
#define NROWS  9216

// Attention config
#define NSPLIT 4             // outer key splits (blockIdx.y)
#define TILES_PER_SPLIT 36   // 9216/64/NSPLIT
#define TILES_PER_WAVE  9    // TILES_PER_SPLIT / 4 waves

#define CSC 0.02944245f      // 1/(49*ln2): S_mfma = qk/(49 ln2); exp2(S)=exp(qk/49)

// ws layout (bytes):
//   yf    bf16 [9216][64] : 0          .. 1179648
//   yfT   bf16 [64][9216] : 1179648    .. 2359296
//   opart bf16 [4][56][9216]: 2359296  .. 6488064
//   esum  f32  [4][9216]  : 6488064    .. 6635520
//   yhat  f32  [144][3136]: 0 (aliases yf/yfT, dead after attn)
#define YF_B    0
#define YFT_B   1179648
#define OPART_B 2359296
#define ESUM_B  6488064
#define YHAT_B  0

__device__ __forceinline__ ushort f32_to_bf16_rne(float x) {
  uint b = __float_as_uint(x);
  b += 0x7fffu + ((b >> 16) & 1u);
  return (ushort)(b >> 16);
}
__device__ __forceinline__ float bf16_to_f32(ushort u) {
  return __uint_as_float(((uint)u) << 16);
}

// ---------------------------------------------------------------------------
// Kernel 1: depthwise convs -> yf bf16 [r][64], r = g*144+c3, t = flat%49.
// ---------------------------------------------------------------------------
__global__ __launch_bounds__(256) void conv_kernel(
    const float* __restrict__ x, const float* __restrict__ w3,
    const float* __restrict__ w5, const float* __restrict__ w7,
    ushort* __restrict__ yf) {
  int idx = blockIdx.x * 256 + threadIdx.x;   // r*64 + t
  int r = idx >> 6, t = idx & 63;
  ushort outv = 0;
  if (t < DW) {
    int g = r / C3, c3 = r - g * C3;
    int flat = g * DW + t;
    int h = flat / HW, w = flat - h * HW;
    int grp = c3 / C_IN, c = c3 - grp * C_IN;
    const float* wk; int ks;
    if (grp == 0)      { wk = w3 + c * 9;  ks = 3; }
    else if (grp == 1) { wk = w5 + c * 25; ks = 5; }
    else               { wk = w7 + c * 49; ks = 7; }
    int p = ks >> 1;
    const float* xc = x + c * SSP;
    float val = 0.f;
    for (int dy = 0; dy < ks; dy++) {
      int hy = h + dy - p;
      if (hy < 0 || hy >= HW) continue;
      const float* xr = xc + hy * HW;
      const float* wr = wk + dy * ks;
      for (int dx = 0; dx < ks; dx++) {
        int wx = w + dx - p;
        if (wx < 0 || wx >= HW) continue;
        val += xr[wx] * wr[dx];
      }
    }
    outv = f32_to_bf16_rne(val);
  }
  yf[idx] = outv;
}

// ---------------------------------------------------------------------------
// Kernel 2: transpose yf [9216][64] -> yfT [64][9216]
// ---------------------------------------------------------------------------
__global__ __launch_bounds__(256) void transpose_kernel(
    const ushort* __restrict__ yf, ushort* __restrict__ yfT) {
  __shared__ ushort tile[64][72];
  int r0 = blockIdx.x * 64;
  int tid = threadIdx.x;
  int rr = tid >> 2, cb = (tid & 3) * 16;
  *(bf16x8*)&tile[rr][cb]     = *(const bf16x8*)&yf[(r0 + rr) * 64 + cb];
  *(bf16x8*)&tile[rr][cb + 8] = *(const bf16x8*)&yf[(r0 + rr) * 64 + cb + 8];
  __syncthreads();
  int t = tid >> 2, rb = (tid & 3) * 16;
  ushort tmp[16];
#pragma unroll
  for (int i = 0; i < 16; i++) tmp[i] = tile[rb + i][t];
  *(bf16x8*)&yfT[t * NROWS + r0 + rb]     = *(bf16x8*)&tmp[0];
  *(bf16x8*)&yfT[t * NROWS + r0 + rb + 8] = *(bf16x8*)&tmp[8];
}

// ---------------------------------------------------------------------------
// Kernel 3: barrier-free MFMA flash attention (no-max softmax: |s|<=~0.5).
// Grid (288, 4): 288 row-blocks of M=32, 4 key splits. Block = 4 waves; each
// wave covers all 32 rows x its private 576-key range (9 tiles of 64).
// S^T = K·Q^T so P packs into wave-private LDS with b64 writes.
// ---------------------------------------------------------------------------
__global__ __launch_bounds__(256, 4) void attn_kernel(
    const ushort* __restrict__ yf, const ushort* __restrict__ yfT,
    ushort* __restrict__ opart, float* __restrict__ esum_g) {
  // union: per-wave P regions (4*32*72*2 = 18432 B) THEN reduction buffer
  __shared__ __align__(16) char smem[4 * 64 * 33 * 4 + 4 * 32 * 4];  // 34304 B
  float* red = (float*)smem;                       // [4][64][33]
  float* leb = (float*)(smem + 4 * 64 * 33 * 4);   // [4][32]

  const int tid = threadIdx.x;
  const int w = tid >> 6, lane = tid & 63;
  const int q = lane >> 4, c = lane & 15;
  const int m0 = blockIdx.x * 32;
  const int sp = blockIdx.y;
  ushort* Pm = (ushort*)smem + w * (32 * 72);      // wave-private P [32][72]

  // Q B-frags (pre-scaled by CSC), once per block: qf[mt][ds]
  bf16x8 qf[2][2];
#pragma unroll
  for (int mt = 0; mt < 2; mt++)
#pragma unroll
    for (int ds = 0; ds < 2; ds++) {
      int m = m0 + mt * 16 + c;
      short tmp[8];
#pragma unroll
      for (int j = 0; j < 8; j++) {
        int d = ds * 32 + q * 8 + j;
        float v = bf16_to_f32(yfT[d * NROWS + m]) * CSC;
        tmp[j] = (short)f32_to_bf16_rne(v);
      }
      qf[mt][ds] = *(bf16x8*)tmp;
    }

  f32x4 o[4][2];
#pragma unroll
  for (int dt = 0; dt < 4; dt++)
#pragma unroll
    for (int mt = 0; mt < 2; mt++) o[dt][mt] = (f32x4)0.f;
  float le[2] = {0.f, 0.f};

  const int ktbase = sp * TILES_PER_SPLIT + w * TILES_PER_WAVE;
  for (int it = 0; it < TILES_PER_WAVE; it++) {
    const int k0 = (ktbase + it) * 64;

    // ---- S^T = K . Q^T ----
    f32x4 s[4][2];
#pragma unroll
    for (int nt = 0; nt < 4; nt++) {
      s[nt][0] = (f32x4)0.f; s[nt][1] = (f32x4)0.f;
      const ushort* kp = &yf[(k0 + nt * 16 + c) * 64 + q * 8];
      bf16x8 a0 = *(const bf16x8*)kp;
      bf16x8 a1 = *(const bf16x8*)(kp + 32);
      s[nt][0] = __builtin_amdgcn_mfma_f32_16x16x32_bf16(a0, qf[0][0], s[nt][0], 0, 0, 0);
      s[nt][1] = __builtin_amdgcn_mfma_f32_16x16x32_bf16(a0, qf[1][0], s[nt][1], 0, 0, 0);
      s[nt][0] = __builtin_amdgcn_mfma_f32_16x16x32_bf16(a1, qf[0][1], s[nt][0], 0, 0, 0);
      s[nt][1] = __builtin_amdgcn_mfma_f32_16x16x32_bf16(a1, qf[1][1], s[nt][1], 0, 0, 0);
    }

    // ---- p = exp2(s); accumulate l; pack P (trunc bf16) into LDS ----
#pragma unroll
    for (int nt = 0; nt < 4; nt++)
#pragma unroll
      for (int mt = 0; mt < 2; mt++) {
        f32x4 sv = s[nt][mt];
        float p0 = __builtin_amdgcn_exp2f(sv[0]);
        float p1 = __builtin_amdgcn_exp2f(sv[1]);
        float p2 = __builtin_amdgcn_exp2f(sv[2]);
        float p3 = __builtin_amdgcn_exp2f(sv[3]);
        le[mt] += (p0 + p1) + (p2 + p3);
        uint d0 = (__float_as_uint(p0) >> 16) | (__float_as_uint(p1) & 0xffff0000u);
        uint d1 = (__float_as_uint(p2) >> 16) | (__float_as_uint(p3) & 0xffff0000u);
        *(uint2*)&Pm[(mt * 16 + c) * 72 + nt * 16 + q * 4] = make_uint2(d0, d1);
      }

    // ---- O^T += V^T . P^T ----
    bf16x8 bp[2][2];
#pragma unroll
    for (int mt = 0; mt < 2; mt++)
#pragma unroll
      for (int nc = 0; nc < 2; nc++)
        bp[mt][nc] = *(const bf16x8*)&Pm[(mt * 16 + c) * 72 + nc * 32 + q * 8];
#pragma unroll
    for (int dt = 0; dt < 4; dt++)
#pragma unroll
      for (int nc = 0; nc < 2; nc++) {
        bf16x8 av = *(const bf16x8*)&yfT[(dt * 16 + c) * NROWS + k0 + nc * 32 + q * 8];
        o[dt][0] = __builtin_amdgcn_mfma_f32_16x16x32_bf16(av, bp[0][nc], o[dt][0], 0, 0, 0);
        o[dt][1] = __builtin_amdgcn_mfma_f32_16x16x32_bf16(av, bp[1][nc], o[dt][1], 0, 0, 0);
      }
  }

  // full-wave l per query col
  le[0] += __shfl_xor(le[0], 16); le[0] += __shfl_xor(le[0], 32);
  le[1] += __shfl_xor(le[1], 16); le[1] += __shfl_xor(le[1], 32);

  __syncthreads();   // P regions dead; smem becomes reduction buffer
  float* myred = red + (w * 64 + lane) * 33;
#pragma unroll
  for (int dt = 0; dt < 4; dt++)
#pragma unroll
    for (int mt = 0; mt < 2; mt++)
#pragma unroll
      for (int r = 0; r < 4; r++) myred[dt * 8 + mt * 4 + r] = o[dt][mt][r];
  if (q == 0) { leb[w * 32 + c] = le[0]; leb[w * 32 + 16 + c] = le[1]; }
  __syncthreads();

  // wave w reduces d-slice dt=w across the 4 waves' key ranges
#pragma unroll
  for (int i = 0; i < 8; i++) {
    int mt = i >> 2, r = i & 3;
    float v = red[(0 * 64 + lane) * 33 + w * 8 + i] +
              red[(1 * 64 + lane) * 33 + w * 8 + i] +
              red[(2 * 64 + lane) * 33 + w * 8 + i] +
              red[(3 * 64 + lane) * 33 + w * 8 + i];
    int d = w * 16 + q * 4 + r;
    if (d < 56) {
      int m = m0 + mt * 16 + c;
      opart[(sp * 56 + d) * NROWS + m] = f32_to_bf16_rne(v);
    }
  }
  if (w == 0 && lane < 32) {
    float t = leb[lane] + leb[32 + lane] + leb[64 + lane] + leb[96 + lane];
    esum_g[sp * NROWS + m0 + lane] = t;
  }
}

// ---------------------------------------------------------------------------
// Kernel 4: merge splits, normalize, scatter to windowed yhat layout.
// ---------------------------------------------------------------------------
__global__ __launch_bounds__(256) void merge_kernel(
    const ushort* __restrict__ opart, const float* __restrict__ esum_g,
    float* __restrict__ yhat) {
  int idx = blockIdx.x * 256 + threadIdx.x;   // t*9216 + r
  if (idx >= DW * NROWS) return;
  int t = idx / NROWS, r = idx - t * NROWS;
  float es = esum_g[r] + esum_g[NROWS + r] + esum_g[2 * NROWS + r] + esum_g[3 * NROWS + r];
  float ov = bf16_to_f32(opart[(0 * 56 + t) * NROWS + r]) +
             bf16_to_f32(opart[(1 * 56 + t) * NROWS + r]) +
             bf16_to_f32(opart[(2 * 56 + t) * NROWS + r]) +
             bf16_to_f32(opart[(3 * 56 + t) * NROWS + r]);
  float v = ov / es;
  int g = r / C3, c3 = r - g * C3;
  int nh = g >> 3, nw = g & 7;
  int t1 = t / 7, t2 = t - t1 * 7;
  yhat[c3 * SSP + (nh * 7 + t1) * HW + (nw * 7 + t2)] = v;
}

// ---------------------------------------------------------------------------
// Kernel 5: pointwise 48x144 + bias + residual.
// ---------------------------------------------------------------------------
__global__ __launch_bounds__(256) void pw_kernel(
    const float* __restrict__ x, const float* __restrict__ pw,
    const float* __restrict__ pb, const float* __restrict__ yhat,
    float* __restrict__ out) {
  int idx = blockIdx.x * 256 + threadIdx.x;  // (o, s/4)
  if (idx >= C_IN * (SSP / 4)) return;
  int o = idx / (SSP / 4), s = (idx - o * (SSP / 4)) * 4;
  float4 acc = *(const float4*)&x[o * SSP + s];
  float b = pb[o];
  acc.x += b; acc.y += b; acc.z += b; acc.w += b;
  const float* pwo = pw + o * C3;
  for (int i = 0; i < C3; i++) {
    float wv = pwo[i];
    float4 v = *(const float4*)&yhat[i * SSP + s];
    acc.x += wv * v.x; acc.y += wv * v.y; acc.z += wv * v.z; acc.w += wv * v.w;
  }
  *(float4*)&out[o * SSP + s] = acc;
}

// ---------------------------------------------------------------------------
extern "C" void kernel_launch(void* const* d_in, const int* in_sizes, int n_in,
                              void* d_out, int out_size, void* d_ws, size_t ws_size,
                              hipStream_t stream) {
  const float* x  = (const float*)d_in[0];
  const float* w3 = (const float*)d_in[1];
  const float* w5 = (const float*)d_in[2];
  const float* w7 = (const float*)d_in[3];
  const float* pw = (const float*)d_in[4];
  const float* pb = (const float*)d_in[5];
  float* out = (float*)d_out;
  char* ws = (char*)d_ws;

  ushort* yf    = (ushort*)(ws + YF_B);
  ushort* yfT   = (ushort*)(ws + YFT_B);
  ushort* opart = (ushort*)(ws + OPART_B);
  float*  esum  = (float*)(ws + ESUM_B);
  float*  yhat  = (float*)(ws + YHAT_B);   // aliases yf/yfT (dead after attn)

  conv_kernel<<<(NROWS * DPAD) / 256, 256, 0, stream>>>(x, w3, w5, w7, yf);
  transpose_kernel<<<NROWS / 64, 256, 0, stream>>>(yf, yfT);
  attn_kernel<<<dim3(NROWS / 32, NSPLIT), 256, 0, stream>>>(yf, yfT, opart, esum);
  merge_kernel<<<(DW * NROWS) / 256, 256, 0, stream>>>(opart, esum, yhat);
  pw_kernel<<<(C_IN * SSP / 4) / 256, 256, 0, stream>>>(x, pw, pb, yhat, out);
}